// Round 1
// baseline (16.181 us; speedup 1.0000x reference)
//
#include <hip/hip_runtime.h>
#include <math.h>

#define K 4
#define TILE 256

struct c32 { float x, y; };
__device__ __forceinline__ c32 cmul(c32 a, c32 b) {
    return { a.x*b.x - a.y*b.y, a.x*b.y + a.y*b.x };
}

__global__ __launch_bounds__(TILE) void qconv4_kernel(
    const float* __restrict__ x, const float* __restrict__ w,
    float* __restrict__ out, int N, int L)
{
    // per element: {A0.re, A0.im, A1.re, A1.im}
    __shared__ float4 amp[TILE + K - 1];

    const int b   = blockIdx.y;
    const int l0  = blockIdx.x * TILE;
    const int tid = threadIdx.x;
    const float* __restrict__ row = x + (size_t)b * N;

    // Stage per-element qubit amplitudes (each element reused by 4 patches).
    for (int e = tid; e < TILE + K - 1; e += TILE) {
        int idx = l0 + e;
        float v = (idx < N) ? row[idx] : 0.0f;
        float a  = atanf(v);
        float bb = atanf(v * v);
        float sa, ca, sb, cb;
        sincosf(0.5f * a,  &sa, &ca);
        sincosf(0.5f * bb, &sb, &cb);
        // A[0] = cos(a/2) e^{-i b/2},  A[1] = sin(a/2) e^{+i b/2}
        amp[e] = make_float4(ca * cb, -ca * sb, sa * cb, sa * sb);
    }
    __syncthreads();

    const int l = l0 + tid;
    if (l >= L) return;

    c32 A[K][2];
    #pragma unroll
    for (int q = 0; q < K; ++q) {
        float4 t = amp[tid + q];
        A[q][0] = { t.x, t.y };
        A[q][1] = { t.z, t.w };
    }

    // Rot(phi, theta, omega) on qubit 0:
    // R00 = e^{-i a} ct, R01 = -e^{+i be} st, R10 = e^{-i be} st, R11 = e^{+i a} ct
    // with a = (phi+omega)/2, be = (phi-omega)/2
    const float phi = w[0], theta = w[1], omega = w[2];
    float ct, st, ca_, sa_, cb_, sb_;
    sincosf(0.5f * theta,         &st,  &ct);
    sincosf(0.5f * (phi + omega), &sa_, &ca_);
    sincosf(0.5f * (phi - omega), &sb_, &cb_);
    const c32 R00 = {  ct * ca_, -ct * sa_ };
    const c32 R01 = { -st * cb_, -st * sb_ };
    const c32 R10 = {  st * cb_, -st * sb_ };
    const c32 R11 = {  ct * ca_,  ct * sa_ };

    // Pair products: H[p][q] = A0[p]*A1[q], T[p][q] = A2[p]*A3[q]
    c32 H[2][2], T[2][2];
    #pragma unroll
    for (int p = 0; p < 2; ++p)
        #pragma unroll
        for (int q = 0; q < 2; ++q) {
            H[p][q] = cmul(A[0][p], A[1][q]);
            T[p][q] = cmul(A[2][p], A[3][q]);
        }

    // CNOT ring = index permutation:
    // psi[i0,i1,i2,i3] = A0[i0^i3] A1[i1^i0^i3] A2[i2^i1] A3[i3^i2]
    float ez = 0.0f;
    #pragma unroll
    for (int i1 = 0; i1 < 2; ++i1)
        #pragma unroll
        for (int i2 = 0; i2 < 2; ++i2)
            #pragma unroll
            for (int i3 = 0; i3 < 2; ++i3) {
                c32 tail = T[i2 ^ i1][i3 ^ i2];
                c32 u = cmul(H[i3][i1 ^ i3], tail);          // i0 = 0
                c32 v = cmul(H[i3 ^ 1][i1 ^ i3 ^ 1], tail);  // i0 = 1
                c32 w0 = { R00.x*u.x - R00.y*u.y + R01.x*v.x - R01.y*v.y,
                           R00.x*u.y + R00.y*u.x + R01.x*v.y + R01.y*v.x };
                c32 w1 = { R10.x*u.x - R10.y*u.y + R11.x*v.x - R11.y*v.y,
                           R10.x*u.y + R10.y*u.x + R11.x*v.y + R11.y*v.x };
                ez += (w0.x*w0.x + w0.y*w0.y) - (w1.x*w1.x + w1.y*w1.y);
            }

    out[(size_t)b * L + l] = ez;
}

extern "C" void kernel_launch(void* const* d_in, const int* in_sizes, int n_in,
                              void* d_out, int out_size, void* d_ws, size_t ws_size,
                              hipStream_t stream) {
    const float* x = (const float*)d_in[0];
    const float* w = (const float*)d_in[1];
    float* out = (float*)d_out;

    const int B = 128;
    const int N = in_sizes[0] / B;   // 8192
    const int L = N - K + 1;         // 8189

    dim3 grid((L + TILE - 1) / TILE, B);
    qconv4_kernel<<<grid, TILE, 0, stream>>>(x, w, out, N, L);
}

// Round 2
// 10.613 us; speedup vs baseline: 1.5246x; 1.5246x over previous
//
#include <hip/hip_runtime.h>
#include <math.h>

#define TPB 256
#define OPT 4   // outputs per thread
#define KQ 4    // kernel size

__global__ __launch_bounds__(TPB) void qconv4_kernel(
    const float* __restrict__ x, const float* __restrict__ w,
    float* __restrict__ out, int N, int L)
{
    const int b = blockIdx.y;
    const int l = (blockIdx.x * TPB + threadIdx.x) * OPT;  // first output of this thread
    if (l >= L) return;

    const float* __restrict__ row = x + (size_t)b * N;

    // Elements l .. l+6 (7 = OPT + KQ - 1). l % 4 == 0 and rows are 16B-aligned,
    // so the float4 load is aligned.
    float xe[OPT + KQ - 1];
    float4 v4 = *reinterpret_cast<const float4*>(row + l);
    xe[0] = v4.x; xe[1] = v4.y; xe[2] = v4.z; xe[3] = v4.w;
    #pragma unroll
    for (int j = 0; j < 3; ++j) {
        int idx = l + 4 + j;
        xe[4 + j] = (idx < N) ? row[idx] : 0.0f;
    }

    // Per element:  c = cos(atan(x))  = rsqrt(1+x^2)
    //               d = cos(atan(x^2))= rsqrt(1+x^4)
    //               g = sin(atan(x))*cos(atan(x^2)) = x*c*d
    //               h = sin(atan(x))*sin(atan(x^2)) = x^2 * g
    float c[OPT + 3], g[OPT + 3], h[OPT + 3];
    #pragma unroll
    for (int e = 0; e < OPT + 3; ++e) {
        float v  = xe[e];
        float t2 = v * v;
        float ce = __builtin_amdgcn_rsqf(1.0f + t2);
        float de = __builtin_amdgcn_rsqf(1.0f + t2 * t2);
        float ge = v * ce * de;
        c[e] = ce;
        g[e] = ge;
        h[e] = t2 * ge;
    }

    // <Z0> = cos(th)*c1*c2*c3 - sin(th)cos(ph)*g0*g1 + sin(th)sin(ph)*g0*h1*c2*c3
    const float ph = w[0], th = w[1];
    float sth, cth, sph, cph;
    sincosf(th, &sth, &cth);
    sincosf(ph, &sph, &cph);
    const float W0 = cth, W1 = -sth * cph, W2 = sth * sph;

    float* __restrict__ orow = out + (size_t)b * L;
    #pragma unroll
    for (int j = 0; j < OPT; ++j) {
        int lj = l + j;
        if (lj < L) {
            float cc = c[j + 2] * c[j + 3];
            float r  = W0 * (c[j + 1] * cc)
                     + W1 * (g[j] * g[j + 1])
                     + W2 * (g[j] * h[j + 1] * cc);
            orow[lj] = r;
        }
    }
}

extern "C" void kernel_launch(void* const* d_in, const int* in_sizes, int n_in,
                              void* d_out, int out_size, void* d_ws, size_t ws_size,
                              hipStream_t stream) {
    const float* x = (const float*)d_in[0];
    const float* w = (const float*)d_in[1];
    float* out = (float*)d_out;

    const int B = 128;
    const int N = in_sizes[0] / B;   // 8192
    const int L = N - KQ + 1;        // 8189

    dim3 grid((L + TPB * OPT - 1) / (TPB * OPT), B);
    qconv4_kernel<<<grid, TPB, 0, stream>>>(x, w, out, N, L);
}

// Round 3
// 10.082 us; speedup vs baseline: 1.6050x; 1.0527x over previous
//
#include <hip/hip_runtime.h>
#include <math.h>

#define TPB 256
#define KQ 4

__device__ __forceinline__ void elemCGH(float v, float& c, float& g, float& h) {
    float t2 = v * v;
    c = __builtin_amdgcn_rsqf(1.0f + t2);        // cos(atan(x))
    float d = __builtin_amdgcn_rsqf(1.0f + t2 * t2); // cos(atan(x^2))
    g = v * c * d;                                // sin(atan(x))cos(atan(x^2))
    h = t2 * g;                                   // sin(atan(x))sin(atan(x^2))
}

__device__ __forceinline__ float qout1(const float* __restrict__ row, int p,
                                       float W0, float W1, float W2) {
    float c0, g0, h0, c1, g1, h1, c2, g2, h2, c3, g3, h3;
    elemCGH(row[p],     c0, g0, h0);
    elemCGH(row[p + 1], c1, g1, h1);
    elemCGH(row[p + 2], c2, g2, h2);
    elemCGH(row[p + 3], c3, g3, h3);
    float cc = c2 * c3;
    return W0 * (c1 * cc) + W1 * (g0 * g1) + W2 * (g0 * h1 * cc);
}

__global__ __launch_bounds__(TPB) void qconv4_kernel(
    const float* __restrict__ x, const float* __restrict__ w,
    float* __restrict__ out, int N, int L)
{
    const int b = blockIdx.y;
    const float* __restrict__ row  = x   + (size_t)b * N;
    float* __restrict__       orow = out + (size_t)b * L;

    // Row b's output starts at flat index b*L, L % 4 == 1 -> start ≡ b (mod 4).
    // Shift by a so groups of 4 outputs are 16B-aligned for float4 stores.
    const int a = (4 - (b & 3)) & 3;
    const int ngroups = (L - a) >> 2;

    // Rot weights: <Z> = cos(th)*c1c2c3 - sin(th)cos(ph)*g0g1 + sin(th)sin(ph)*g0h1c2c3
    const float ph = w[0], th = w[1];
    float sth, cth, sph, cph;
    __sincosf(th, &sth, &cth);
    __sincosf(ph, &sph, &cph);
    const float W0 = cth, W1 = -sth * cph, W2 = sth * sph;

    const int j = blockIdx.x * TPB + threadIdx.x;

    if (j < ngroups) {
        const int l = a + 4 * j;   // first output; needs x[l .. l+6], l+6 <= 8191 < N
        float c[7], g[7], h[7];
        #pragma unroll
        for (int e = 0; e < 7; ++e)
            elemCGH(row[l + e], c[e], g[e], h[e]);

        float4 r;
        float* rp = &r.x;
        #pragma unroll
        for (int e = 0; e < 4; ++e) {
            float cc = c[e + 2] * c[e + 3];
            rp[e] = W0 * (c[e + 1] * cc) + W1 * (g[e] * g[e + 1]) + W2 * (g[e] * h[e + 1] * cc);
        }
        *reinterpret_cast<float4*>(orow + l) = r;   // 16B-aligned
    } else if (j == ngroups) {
        // prefix [0, a) and tail [a + 4*ngroups, L)
        for (int p = 0; p < a; ++p)
            orow[p] = qout1(row, p, W0, W1, W2);
        for (int p = a + 4 * ngroups; p < L; ++p)
            orow[p] = qout1(row, p, W0, W1, W2);
    }
}

extern "C" void kernel_launch(void* const* d_in, const int* in_sizes, int n_in,
                              void* d_out, int out_size, void* d_ws, size_t ws_size,
                              hipStream_t stream) {
    const float* x = (const float*)d_in[0];
    const float* w = (const float*)d_in[1];
    float* out = (float*)d_out;

    const int B = 128;
    const int N = in_sizes[0] / B;   // 8192
    const int L = N - KQ + 1;        // 8189

    // max threads needed per row: ngroups(+1 cleanup) <= 2048
    dim3 grid(2048 / TPB, B);
    qconv4_kernel<<<grid, TPB, 0, stream>>>(x, w, out, N, L);
}

// Round 4
// 9.748 us; speedup vs baseline: 1.6600x; 1.0343x over previous
//
#include <hip/hip_runtime.h>
#include <math.h>

#define TPB 256
#define KQ 4
#define OPT 8   // outputs per thread

__device__ __forceinline__ void elemCGH(float v, float& c, float& g, float& h) {
    float t2 = v * v;
    c = __builtin_amdgcn_rsqf(1.0f + t2);            // cos(atan(x))
    float d = __builtin_amdgcn_rsqf(1.0f + t2 * t2); // cos(atan(x^2))
    g = v * c * d;                                   // sin(atan(x))cos(atan(x^2))
    h = t2 * g;                                      // sin(atan(x))sin(atan(x^2))
}

__device__ __forceinline__ float qout1(const float* __restrict__ row, int p,
                                       float W0, float W1, float W2) {
    float c0, g0, h0, c1, g1, h1, c2, g2, h2, c3, g3, h3;
    elemCGH(row[p],     c0, g0, h0);
    elemCGH(row[p + 1], c1, g1, h1);
    elemCGH(row[p + 2], c2, g2, h2);
    elemCGH(row[p + 3], c3, g3, h3);
    float cc = c2 * c3;
    return W0 * (c1 * cc) + W1 * (g0 * g1) + W2 * (g0 * h1 * cc);
}

__global__ __launch_bounds__(TPB) void qconv4_kernel(
    const float* __restrict__ x, const float* __restrict__ w,
    float* __restrict__ out, int N, int L)
{
    const int b = blockIdx.y;
    const float* __restrict__ row  = x   + (size_t)b * N;
    float* __restrict__       orow = out + (size_t)b * L;

    // Row b's outputs start at flat index b*L; L % 4 == 1 -> start ≡ b (mod 4).
    // Shift by a so each thread's 8 outputs form two 16B-aligned float4 stores.
    const int a = (4 - (b & 3)) & 3;
    const int ngroups = (L - a) >> 3;   // groups of 8

    // <Z> = cos(th)*c1c2c3 - sin(th)cos(ph)*g0g1 + sin(th)sin(ph)*g0h1c2c3
    const float ph = w[0], th = w[1];
    float sth, cth, sph, cph;
    __sincosf(th, &sth, &cth);
    __sincosf(ph, &sph, &cph);
    const float W0 = cth, W1 = -sth * cph, W2 = sth * sph;

    const int j = blockIdx.x * TPB + threadIdx.x;

    if (j < ngroups) {
        const int l = a + OPT * j;  // needs x[l .. l+10]; max l+10 <= 8189 < N
        float c[OPT + 3], g[OPT + 3], h[OPT + 3];
        #pragma unroll
        for (int e = 0; e < OPT + 3; ++e)
            elemCGH(row[l + e], c[e], g[e], h[e]);

        float r[OPT];
        #pragma unroll
        for (int e = 0; e < OPT; ++e) {
            float cc = c[e + 2] * c[e + 3];
            r[e] = W0 * (c[e + 1] * cc) + W1 * (g[e] * g[e + 1]) + W2 * (g[e] * h[e + 1] * cc);
        }
        *reinterpret_cast<float4*>(orow + l)     = make_float4(r[0], r[1], r[2], r[3]);
        *reinterpret_cast<float4*>(orow + l + 4) = make_float4(r[4], r[5], r[6], r[7]);
    }
    if (j == 0) {
        // prefix [0, a) and tail [a + 8*ngroups, L) — ≤ 10 scalar outputs
        for (int p = 0; p < a; ++p)
            orow[p] = qout1(row, p, W0, W1, W2);
        for (int p = a + OPT * ngroups; p < L; ++p)
            orow[p] = qout1(row, p, W0, W1, W2);
    }
}

extern "C" void kernel_launch(void* const* d_in, const int* in_sizes, int n_in,
                              void* d_out, int out_size, void* d_ws, size_t ws_size,
                              hipStream_t stream) {
    const float* x = (const float*)d_in[0];
    const float* w = (const float*)d_in[1];
    float* out = (float*)d_out;

    const int B = 128;
    const int N = in_sizes[0] / B;   // 8192
    const int L = N - KQ + 1;        // 8189

    // per row: ngroups <= 1023 threads (+ thread 0 cleanup) -> 4 blocks of 256
    dim3 grid(4, B);
    qconv4_kernel<<<grid, TPB, 0, stream>>>(x, w, out, N, L);
}